// Round 7
// baseline (531.550 us; speedup 1.0000x reference)
//
#include <hip/hip_runtime.h>
#include <math.h>

#define BN 32768
#define INDP 352      // padded input width (336 -> 352, zero-filled)
#define HD 256
#define AD 64
#define EN 16
#define TME 32        // expert tile rows
#define TMG 16        // gate tile rows
#define STOT (BN * 4)
#define GRID_E 4112   // 8 * 514 >= max tiles (4111)
#define CHUNK_E 514

typedef __attribute__((ext_vector_type(8))) short s8v;
typedef __attribute__((ext_vector_type(4))) float f4v;
typedef unsigned short u16;

__device__ __forceinline__ u16 f2bf(float x) {
  unsigned u = __float_as_uint(x);
  return (u16)((u + 0x7fffu + ((u >> 16) & 1u)) >> 16);
}
__device__ __forceinline__ float bf2f(u16 h) { return __uint_as_float(((unsigned)h) << 16); }
__device__ __forceinline__ float rcpf(float a) { float r; asm("v_rcp_f32 %0, %1" : "=v"(r) : "v"(a)); return r; }
// mish(x) = x*tanh(softplus(x)) = x*(u^2+2u)/(u^2+2u+2), u=e^x (exact algebraic rewrite)
__device__ __forceinline__ float mishf(float x) {
  float xc = fminf(x, 30.f);
  float u = __expf(xc);
  float w = fmaf(u, u, u + u);
  return x * w * rcpf(w + 2.f);
}
__device__ __forceinline__ f4v mfma16(s8v a, s8v b, f4v c) {
  return __builtin_amdgcn_mfma_f32_16x16x32_bf16(a, b, c, 0, 0, 0);
}
__device__ __forceinline__ void pack8(const u16* q, u16* d) {
  uint4 u;
  u.x = q[0] | ((unsigned)q[1] << 16); u.y = q[2] | ((unsigned)q[3] << 16);
  u.z = q[4] | ((unsigned)q[5] << 16); u.w = q[6] | ((unsigned)q[7] << 16);
  *(uint4*)d = u;
}

// ---------------- init (scalars only; out no longer needs zeroing) ----------------
__global__ void k_init(int* __restrict__ counts, int* __restrict__ cursor,
                       float* __restrict__ ent) {
  int i = threadIdx.x;
  if (i < 16) { counts[i] = 0; cursor[i] = 0; }
  if (i == 16) *ent = 0.f;
}

// ------- weight prep: fp32 [K][N] -> fragment-ordered split-bf16 planes -------
// dst (u16 units): [s][nt][plane 0..NP-1][lane 0..63][8]; elem i of lane l:
//   k = s*32 + 8*(l>>4) + i, n = nt*16 + (l&15)
__global__ void k_prep(const float* __restrict__ src, u16* __restrict__ dst,
                       int Ksrc, int Spad, int NT, int N,
                       long sStride, long dStride, int NP, int total) {
  int idx = blockIdx.x * 256 + threadIdx.x;
  if (idx >= total) return;
  int l = idx & 63;
  int t = idx >> 6;
  int nt = t % NT; t /= NT;
  int s = t % Spad; t /= Spad;
  int m = t;
  const float* sp = src + (size_t)m * sStride;
  int n = nt * 16 + (l & 15);
  int kb = s * 32 + (l >> 4) * 8;
  u16 q0[8], q1[8], q2[8];
  #pragma unroll
  for (int i = 0; i < 8; ++i) {
    int k = kb + i;
    float v = (k < Ksrc) ? sp[(size_t)k * N + n] : 0.f;
    u16 a = f2bf(v); float r1 = v - bf2f(a);
    u16 b = f2bf(r1); float r2 = r1 - bf2f(b);
    q0[i] = a; q1[i] = b; q2[i] = f2bf(r2);
  }
  u16* d = dst + (size_t)m * dStride + (size_t)((s * NT + nt) * NP) * 512 + l * 8;
  pack8(q0, d);
  pack8(q1, d + 512);
  if (NP == 3) pack8(q2, d + 1024);
}

// ------- time embedding + input assembly (3 split-bf16 planes) -------
__global__ void k_time_inp(const float* __restrict__ x, const float* __restrict__ sigma,
                           const float* __restrict__ state,
                           const float* __restrict__ tW1, const float* __restrict__ tb1,
                           const float* __restrict__ tW2, const float* __restrict__ tb2,
                           u16* __restrict__ p0, u16* __restrict__ p1, u16* __restrict__ p2) {
  const int wv = threadIdx.x >> 6;
  const int lane = threadIdx.x & 63;
  const int row = blockIdx.x * 4 + wv;
  const float sg = sigma[row];
  const float rt = 250.0f * logf(sg + 1e-44f);
  float pe = 0.f;
  if (lane < 16) {
    int j = lane & 7;
    float f = expf(-1.3157629102823121f * (float)j);  // -ln(10000)/7 * j
    float ang = rt * f;
    pe = (lane < 8) ? sinf(ang) : cosf(ang);
  }
  float h1;
  {
    float acc = 0.f;
    int j = lane & 31;
    #pragma unroll
    for (int i = 0; i < 16; ++i) {
      float p = __shfl(pe, i, 64);
      acc = fmaf(p, tW1[i * 32 + j], acc);
    }
    acc += tb1[j];
    float sp = log1pf(expf(acc));
    h1 = acc * tanhf(sp);
  }
  float t2;
  {
    float acc = 0.f;
    int j = lane & 15;
    #pragma unroll
    for (int i = 0; i < 32; ++i) {
      float h = __shfl(h1, i, 64);
      acc = fmaf(h, tW2[i * 16 + j], acc);
    }
    t2 = acc + tb2[j];
  }
  const float c_in = rsqrtf(sg * sg + 0.25f);
  u16* r0 = p0 + (size_t)row * INDP;
  u16* r1 = p1 + (size_t)row * INDP;
  u16* r2 = p2 + (size_t)row * INDP;
  auto wsplit = [&](int c, float v) {
    u16 a = f2bf(v); float ra = v - bf2f(a);
    u16 b = f2bf(ra); float rb = ra - bf2f(b);
    r0[c] = a; r1[c] = b; r2[c] = f2bf(rb);
  };
  wsplit(lane, c_in * x[row * 64 + lane]);
  if (lane < 16) wsplit(64 + lane, t2);
  #pragma unroll
  for (int r = 0; r < 4; ++r)
    wsplit(80 + r * 64 + lane, state[(size_t)row * 256 + r * 64 + lane]);
  if (lane < 16) { r0[336 + lane] = 0; r1[336 + lane] = 0; r2[336 + lane] = 0; }
}

// ------- gate: TMG=16, all-MFMA (6-term L1, 6-term L2), 3 H-planes in LDS -------
__global__ __launch_bounds__(256, 4) void k_gate(
    const u16* __restrict__ p0, const u16* __restrict__ p1, const u16* __restrict__ p2,
    const u16* __restrict__ gW1b, const float* __restrict__ gb1,
    const u16* __restrict__ gW2b, const float* __restrict__ gb2,
    int* __restrict__ topk_idx, float* __restrict__ topk_w,
    int* __restrict__ counts, float* __restrict__ ent_sum) {
  __shared__ __align__(16) u16 sH0[TMG * 256];
  __shared__ __align__(16) u16 sH1[TMG * 256];
  __shared__ __align__(16) u16 sH2[TMG * 256];
  __shared__ float sLog[TMG * 16];
  __shared__ int scnt[16];
  const int tid = threadIdx.x;
  const int l = tid & 63, wn = tid >> 6;
  const int g = l >> 4, r16 = l & 15;
  const int row0 = blockIdx.x * TMG;
  const int swz = (r16 & 7) << 3;
  if (tid < 16) scnt[tid] = 0;

  f4v acc[4];
  #pragma unroll
  for (int j = 0; j < 4; ++j) acc[j] = (f4v){0.f, 0.f, 0.f, 0.f};

  #pragma unroll
  for (int s = 0; s < 11; ++s) {
    s8v a0, a1, a2, b0[4], b1[4], b2[4];
    {
      size_t off = (size_t)(row0 + r16) * INDP + s * 32 + g * 8;
      a0 = *(const s8v*)(p0 + off);
      a1 = *(const s8v*)(p1 + off);
      a2 = *(const s8v*)(p2 + off);
    }
    #pragma unroll
    for (int j = 0; j < 4; ++j) {
      const u16* pb = gW1b + (size_t)((s * 16 + wn * 4 + j) * 3) * 512 + l * 8;
      b0[j] = *(const s8v*)pb;
      b1[j] = *(const s8v*)(pb + 512);
      b2[j] = *(const s8v*)(pb + 1024);
    }
    #pragma unroll
    for (int j = 0; j < 4; ++j) acc[j] = mfma16(a0, b0[j], acc[j]);
    #pragma unroll
    for (int j = 0; j < 4; ++j) acc[j] = mfma16(a0, b1[j], acc[j]);
    #pragma unroll
    for (int j = 0; j < 4; ++j) acc[j] = mfma16(a1, b0[j], acc[j]);
    #pragma unroll
    for (int j = 0; j < 4; ++j) acc[j] = mfma16(a1, b1[j], acc[j]);
    #pragma unroll
    for (int j = 0; j < 4; ++j) acc[j] = mfma16(a0, b2[j], acc[j]);
    #pragma unroll
    for (int j = 0; j < 4; ++j) acc[j] = mfma16(a2, b0[j], acc[j]);
  }
  // relu + 3-way split into LDS planes (swizzled)
  #pragma unroll
  for (int j = 0; j < 4; ++j) {
    float bj = gb1[wn * 64 + j * 16 + r16];
    #pragma unroll
    for (int r = 0; r < 4; ++r) {
      int row = g * 4 + r;
      int col = wn * 64 + j * 16 + r16;
      float v = fmaxf(acc[j][r] + bj, 0.f);
      u16 h0 = f2bf(v); float ra = v - bf2f(h0);
      u16 h1 = f2bf(ra); float rb = ra - bf2f(h1);
      int ec = col ^ ((row & 7) << 3);
      sH0[row * 256 + ec] = h0;
      sH1[row * 256 + ec] = h1;
      sH2[row * 256 + ec] = f2bf(rb);
    }
  }
  __syncthreads();

  // L2: 256 -> 16, 6-term, all waves compute redundantly (B frags from global)
  f4v l2 = (f4v){0.f, 0.f, 0.f, 0.f};
  #pragma unroll
  for (int s = 0; s < 8; ++s) {
    const u16* pb = gW2b + (size_t)(s * 3) * 512 + l * 8;
    s8v b0 = *(const s8v*)pb;
    s8v b1 = *(const s8v*)(pb + 512);
    s8v b2 = *(const s8v*)(pb + 1024);
    int ec = (s * 32 + g * 8) ^ swz;
    s8v a0 = *(const s8v*)&sH0[r16 * 256 + ec];
    s8v a1 = *(const s8v*)&sH1[r16 * 256 + ec];
    s8v a2 = *(const s8v*)&sH2[r16 * 256 + ec];
    l2 = mfma16(a0, b0, l2);
    l2 = mfma16(a0, b1, l2);
    l2 = mfma16(a1, b0, l2);
    l2 = mfma16(a1, b1, l2);
    l2 = mfma16(a0, b2, l2);
    l2 = mfma16(a2, b0, l2);
  }
  if (wn == 0) {
    #pragma unroll
    for (int r = 0; r < 4; ++r)
      sLog[(g * 4 + r) * 16 + r16] = l2[r] + gb2[r16];
  }
  __syncthreads();

  float entc = 0.f;
  if (tid < TMG) {
    const int row = row0 + tid;
    float gx[16], mx = -1e30f;
    #pragma unroll
    for (int e = 0; e < 16; ++e) { gx[e] = sLog[tid * 16 + e]; mx = fmaxf(mx, gx[e]); }
    float p[16], s = 0.f;
    #pragma unroll
    for (int e = 0; e < 16; ++e) { p[e] = expf(gx[e] - mx); s += p[e]; }
    const float inv = 1.f / s;
    #pragma unroll
    for (int e = 0; e < 16; ++e) {
      float pr = p[e] * inv;
      entc -= pr * logf(pr + 1e-9f);
    }
    int idxs[4]; float scs[4];
    unsigned used = 0;
    float wsum = 1e-9f;
    #pragma unroll
    for (int k = 0; k < 4; ++k) {
      int be = 0; float bv = -1.f;
      #pragma unroll
      for (int e = 0; e < 16; ++e) {
        float pr = p[e] * inv;
        if (!((used >> e) & 1u) && pr > bv) { bv = pr; be = e; }
      }
      used |= (1u << be);
      idxs[k] = be; scs[k] = bv;
      wsum += bv;
    }
    #pragma unroll
    for (int k = 0; k < 4; ++k) {
      topk_idx[row * 4 + k] = idxs[k];
      topk_w[row * 4 + k] = scs[k] / wsum;
      atomicAdd(&scnt[idxs[k]], 1);
    }
  }
  if (tid < 64) {
    #pragma unroll
    for (int off = 32; off > 0; off >>= 1) entc += __shfl_down(entc, off, 64);
  }
  if (tid == 0) atomicAdd(ent_sum, entc);
  __syncthreads();
  if (tid < 16 && scnt[tid] > 0) atomicAdd(&counts[tid], scnt[tid]);
}

// ---------------- offsets + aux loss ----------------
__global__ void k_aux(const int* __restrict__ counts, const float* __restrict__ ent_sum,
                      int* __restrict__ offsets, int* __restrict__ tbk,
                      float* __restrict__ aux_out) {
  if (threadIdx.x == 0) {
    int off = 0, t = 0;
    float load[16], mean = 0.f;
    for (int e = 0; e < 16; ++e) {
      offsets[e] = off; tbk[e] = t;
      int c = counts[e];
      off += c;
      t += (c + TME - 1) / TME;
      load[e] = (float)c / (32768.0f + 1e-9f);
      mean += load[e];
    }
    offsets[16] = off; tbk[16] = t;
    mean *= (1.f / 16.f);
    float var = 0.f;
    for (int e = 0; e < 16; ++e) { float d = load[e] - mean; var += d * d; }
    var *= (1.f / 15.f);
    *aux_out = var + ent_sum[0] * (1.0f / 32768.0f);
  }
}

// ------- scatter: block-aggregated; also emits inverse map row -> slots -------
__global__ void k_scatter(const int* __restrict__ topk_idx, const float* __restrict__ topk_w,
                          const int* __restrict__ offsets, int* __restrict__ cursor,
                          int* __restrict__ slot_row, int* __restrict__ rslot) {
  __shared__ int cnt[16];
  __shared__ int base[16];
  const int tid = threadIdx.x;
  if (tid < 16) cnt[tid] = 0;
  __syncthreads();
  const int row = blockIdx.x * 256 + tid;
  int e4[4]; int lp[4];
  #pragma unroll
  for (int k = 0; k < 4; ++k) {
    e4[k] = topk_idx[row * 4 + k];
    lp[k] = atomicAdd(&cnt[e4[k]], 1);
  }
  __syncthreads();
  if (tid < 16) base[tid] = atomicAdd(&cursor[tid], cnt[tid]);
  __syncthreads();
  #pragma unroll
  for (int k = 0; k < 4; ++k) {
    int s = offsets[e4[k]] + base[e4[k]] + lp[k];
    slot_row[s] = row;
    rslot[row * 4 + k] = s;
  }
}

// ------- fused expert: TME=32, 4 waves, 4 blocks/CU; full-unroll pipelined -------
__global__ __launch_bounds__(256, 4) void k_expert(
    const u16* __restrict__ inpHi, const u16* __restrict__ inpLo,
    const u16* __restrict__ eW1b, const float* __restrict__ eb1,
    const u16* __restrict__ eW2b, const float* __restrict__ eb2,
    const u16* __restrict__ eW3b, const float* __restrict__ eb3,
    const u16* __restrict__ fWb,
    const int* __restrict__ offsets, const int* __restrict__ counts,
    const int* __restrict__ tbk, const int* __restrict__ slot_row,
    float* __restrict__ eout) {
  __shared__ __align__(16) u16 sHi[TME * 256];
  __shared__ __align__(16) u16 sLo[TME * 256];
  __shared__ int sRows[TME];

  // XCD-chunked bijective remap
  const int bid = (blockIdx.x & 7) * CHUNK_E + (blockIdx.x >> 3);
  if (bid >= tbk[16]) return;
  int e = 0;
  #pragma unroll
  for (int i = 1; i < 16; ++i)
    if (bid >= tbk[i]) e = i;
  const int tile = bid - tbk[e];
  const int cnt = counts[e];
  const int s0 = offsets[e] + tile * TME;
  const int nr = min(TME, cnt - tile * TME);
  const int tid = threadIdx.x;
  const int l = tid & 63;
  const int wn = tid >> 6;          // 0..3 (N quarter)
  const int g = l >> 4, r16 = l & 15;
  const int swz = (r16 & 7) << 3;

  if (tid < TME)
    sRows[tid] = (tid < nr) ? slot_row[s0 + tid] : slot_row[s0];
  __syncthreads();

  size_t rbase[2];
  #pragma unroll
  for (int mt = 0; mt < 2; ++mt)
    rbase[mt] = (size_t)sRows[mt * 16 + r16] * INDP;

  f4v acc[2][4];
  #pragma unroll
  for (int i = 0; i < 2; ++i)
    #pragma unroll
    for (int j = 0; j < 4; ++j) acc[i][j] = (f4v){0.f, 0.f, 0.f, 0.f};

  // ---- layer 1: K=352, A direct from global planes; full unroll ----
  const u16* W1 = eW1b + (size_t)e * 180224;
  #pragma unroll
  for (int s = 0; s < 11; ++s) {
    s8v ah[2], al[2], bh[4], bl[4];
    #pragma unroll
    for (int mt = 0; mt < 2; ++mt) {
      size_t off = rbase[mt] + s * 32 + g * 8;
      ah[mt] = *(const s8v*)(inpHi + off);
      al[mt] = *(const s8v*)(inpLo + off);
    }
    #pragma unroll
    for (int j = 0; j < 4; ++j) {
      const u16* pb = W1 + (size_t)((s * 16 + wn * 4 + j) * 2) * 512 + l * 8;
      bh[j] = *(const s8v*)pb;
      bl[j] = *(const s8v*)(pb + 512);
    }
    // term-grouped: same-acc MFMAs 8 apart
    #pragma unroll
    for (int mt = 0; mt < 2; ++mt)
      #pragma unroll
      for (int j = 0; j < 4; ++j) acc[mt][j] = mfma16(ah[mt], bh[j], acc[mt][j]);
    #pragma unroll
    for (int mt = 0; mt < 2; ++mt)
      #pragma unroll
      for (int j = 0; j < 4; ++j) acc[mt][j] = mfma16(al[mt], bh[j], acc[mt][j]);
    #pragma unroll
    for (int mt = 0; mt < 2; ++mt)
      #pragma unroll
      for (int j = 0; j < 4; ++j) acc[mt][j] = mfma16(ah[mt], bl[j], acc[mt][j]);
  }
  {
    const float* b1 = eb1 + e * HD;
    #pragma unroll
    for (int mt = 0; mt < 2; ++mt)
      #pragma unroll
      for (int j = 0; j < 4; ++j) {
        float bj = b1[wn * 64 + j * 16 + r16];
        #pragma unroll
        for (int r = 0; r < 4; ++r) {
          int row = mt * 16 + g * 4 + r;
          int col = wn * 64 + j * 16 + r16;
          float v = mishf(acc[mt][j][r] + bj);
          u16 h = f2bf(v);
          int ec = col ^ ((row & 7) << 3);
          sHi[row * 256 + ec] = h;
          sLo[row * 256 + ec] = f2bf(v - bf2f(h));
        }
      }
  }
  __syncthreads();

  // ---- layers 2 & 3: K=256, A from swizzled LDS planes; full unroll ----
  #pragma unroll 1
  for (int L = 0; L < 2; ++L) {
    const u16* Wb = (L == 0 ? eW2b : eW3b) + (size_t)e * 131072;
    const float* bb = (L == 0 ? eb2 : eb3) + e * HD;
    f4v a2[2][4];
    #pragma unroll
    for (int i = 0; i < 2; ++i)
      #pragma unroll
      for (int j = 0; j < 4; ++j) a2[i][j] = (f4v){0.f, 0.f, 0.f, 0.f};
    #pragma unroll
    for (int s = 0; s < 8; ++s) {
      s8v ah[2], al[2], bh[4], bl[4];
      #pragma unroll
      for (int mt = 0; mt < 2; ++mt) {
        int row = mt * 16 + r16;
        int ec = (s * 32 + g * 8) ^ swz;
        ah[mt] = *(const s8v*)&sHi[row * 256 + ec];
        al[mt] = *(const s8v*)&sLo[row * 256 + ec];
      }
      #pragma unroll
      for (int j = 0; j < 4; ++j) {
        const u16* pb = Wb + (size_t)((s * 16 + wn * 4 + j) * 2) * 512 + l * 8;
        bh[j] = *(const s8v*)pb;
        bl[j] = *(const s8v*)(pb + 512);
      }
      #pragma unroll
      for (int mt = 0; mt < 2; ++mt)
        #pragma unroll
        for (int j = 0; j < 4; ++j) a2[mt][j] = mfma16(ah[mt], bh[j], a2[mt][j]);
      #pragma unroll
      for (int mt = 0; mt < 2; ++mt)
        #pragma unroll
        for (int j = 0; j < 4; ++j) a2[mt][j] = mfma16(al[mt], bh[j], a2[mt][j]);
      #pragma unroll
      for (int mt = 0; mt < 2; ++mt)
        #pragma unroll
        for (int j = 0; j < 4; ++j) a2[mt][j] = mfma16(ah[mt], bl[j], a2[mt][j]);
    }
    __syncthreads();  // all reads of previous acts complete
    #pragma unroll
    for (int mt = 0; mt < 2; ++mt)
      #pragma unroll
      for (int j = 0; j < 4; ++j) {
        float bj = bb[wn * 64 + j * 16 + r16];
        #pragma unroll
        for (int r = 0; r < 4; ++r) {
          int row = mt * 16 + g * 4 + r;
          int col = wn * 64 + j * 16 + r16;
          float v = mishf(a2[mt][j][r] + bj);
          u16 h = f2bf(v);
          int ec = col ^ ((row & 7) << 3);
          sHi[row * 256 + ec] = h;
          sLo[row * 256 + ec] = f2bf(v - bf2f(h));
        }
      }
    __syncthreads();
  }

  // ---- final projection: K=256 -> N=64; wave wn owns cols wn*16..+16 ----
  f4v a3[2];
  a3[0] = (f4v){0.f, 0.f, 0.f, 0.f};
  a3[1] = (f4v){0.f, 0.f, 0.f, 0.f};
  #pragma unroll
  for (int s = 0; s < 8; ++s) {
    s8v ah[2], al[2];
    #pragma unroll
    for (int mt = 0; mt < 2; ++mt) {
      int row = mt * 16 + r16;
      int ec = (s * 32 + g * 8) ^ swz;
      ah[mt] = *(const s8v*)&sHi[row * 256 + ec];
      al[mt] = *(const s8v*)&sLo[row * 256 + ec];
    }
    const u16* pb = fWb + (size_t)((s * 4 + wn) * 2) * 512 + l * 8;
    s8v bh = *(const s8v*)pb;
    s8v bl = *(const s8v*)(pb + 512);
    #pragma unroll
    for (int mt = 0; mt < 2; ++mt) {
      a3[mt] = mfma16(ah[mt], bh, a3[mt]);
      a3[mt] = mfma16(al[mt], bh, a3[mt]);
      a3[mt] = mfma16(ah[mt], bl, a3[mt]);
    }
  }
  // plain coalesced-ish stores to slot-indexed scratch (no atomics)
  #pragma unroll
  for (int mt = 0; mt < 2; ++mt)
    #pragma unroll
    for (int r = 0; r < 4; ++r) {
      int rl = mt * 16 + g * 4 + r;
      if (rl < nr)
        eout[(size_t)(s0 + rl) * AD + wn * 16 + r16] = a3[mt][r];
    }
}

// ---------------- epilogue: gather top-4 slots + consistency scalings ----------------
__global__ void k_final(const float* __restrict__ x, const float* __restrict__ sigma,
                        const float* __restrict__ fb, const int* __restrict__ rslot,
                        const float* __restrict__ topk_w, const float* __restrict__ eout,
                        float* __restrict__ out) {
  int i = blockIdx.x * 256 + threadIdx.x;
  if (i >= BN * AD) return;
  int row = i >> 6, c = i & 63;
  float a = 0.f;
  #pragma unroll
  for (int k = 0; k < 4; ++k)
    a = fmaf(topk_w[row * 4 + k], eout[(size_t)rslot[row * 4 + k] * AD + c], a);
  float sg = sigma[row];
  float sm = sg - 0.002f;
  float c_skip = 0.25f / (sm * sm + 0.25f);
  float c_out = sm * 0.5f * rsqrtf(sg * sg + 0.25f);
  float d = c_out * (a + fb[c]) + c_skip * x[i];
  out[i] = fminf(fmaxf(d, -1.f), 1.f);
}

extern "C" void kernel_launch(void* const* d_in, const int* in_sizes, int n_in,
                              void* d_out, int out_size, void* d_ws, size_t ws_size,
                              hipStream_t stream) {
  const float* x     = (const float*)d_in[0];
  const float* sigma = (const float*)d_in[1];
  const float* state = (const float*)d_in[2];
  const float* tW1   = (const float*)d_in[3];
  const float* tb1   = (const float*)d_in[4];
  const float* tW2   = (const float*)d_in[5];
  const float* tb2   = (const float*)d_in[6];
  const float* gW1   = (const float*)d_in[7];
  const float* gb1   = (const float*)d_in[8];
  const float* gW2   = (const float*)d_in[9];
  const float* gb2   = (const float*)d_in[10];
  const float* eW1   = (const float*)d_in[11];
  const float* eb1   = (const float*)d_in[12];
  const float* eW2   = (const float*)d_in[13];
  const float* eb2   = (const float*)d_in[14];
  const float* eW3   = (const float*)d_in[15];
  const float* eb3   = (const float*)d_in[16];
  const float* fW    = (const float*)d_in[17];
  const float* fb    = (const float*)d_in[18];
  float* out = (float*)d_out;

  char* p = (char*)d_ws;
  auto alloc = [&](size_t bytes) { void* r = (void*)p; p += (bytes + 255) & ~(size_t)255; return r; };
  u16* inpHi  = (u16*)alloc((size_t)BN * INDP * 2);
  u16* inpLo  = (u16*)alloc((size_t)BN * INDP * 2);
  u16* inpMid = (u16*)alloc((size_t)BN * INDP * 2);
  u16* gW1b   = (u16*)alloc((size_t)11 * 16 * 3 * 512 * 2);
  u16* gW2b   = (u16*)alloc((size_t)8 * 3 * 512 * 2);
  u16* eW1b   = (u16*)alloc((size_t)16 * 180224 * 2);
  u16* eW2b   = (u16*)alloc((size_t)16 * 131072 * 2);
  u16* eW3b   = (u16*)alloc((size_t)16 * 131072 * 2);
  u16* fWb    = (u16*)alloc((size_t)32768 * 2);
  float* eout = (float*)alloc((size_t)STOT * AD * 4);
  int*   topk_idx = (int*)alloc((size_t)BN * 4 * 4);
  float* topk_w   = (float*)alloc((size_t)BN * 4 * 4);
  int*   rslot    = (int*)alloc((size_t)BN * 4 * 4);
  int*   counts   = (int*)alloc(64);
  int*   cursor   = (int*)alloc(64);
  int*   offsets  = (int*)alloc(68);
  int*   tbk      = (int*)alloc(68);
  float* ent      = (float*)alloc(4);
  int*   slot_row = (int*)alloc((size_t)STOT * 4);

  k_init<<<1, 64, 0, stream>>>(counts, cursor, ent);

  int tot;
  tot = 16 * 11 * 16 * 64;  // experts layer 1
  k_prep<<<(tot + 255) / 256, 256, 0, stream>>>(eW1, eW1b, 336, 11, 16, 256,
                                                (long)336 * 256, 180224, 2, tot);
  tot = 16 * 8 * 16 * 64;   // experts layers 2, 3
  k_prep<<<(tot + 255) / 256, 256, 0, stream>>>(eW2, eW2b, 256, 8, 16, 256,
                                                (long)256 * 256, 131072, 2, tot);
  k_prep<<<(tot + 255) / 256, 256, 0, stream>>>(eW3, eW3b, 256, 8, 16, 256,
                                                (long)256 * 256, 131072, 2, tot);
  tot = 11 * 16 * 64;       // gate layer 1 (3 planes)
  k_prep<<<(tot + 255) / 256, 256, 0, stream>>>(gW1, gW1b, 336, 11, 16, 256,
                                                0, 0, 3, tot);
  tot = 8 * 1 * 64;         // gate layer 2 (3 planes, N=16)
  k_prep<<<(tot + 255) / 256, 256, 0, stream>>>(gW2, gW2b, 256, 8, 1, 16,
                                                0, 0, 3, tot);
  tot = 8 * 4 * 64;         // final projection
  k_prep<<<(tot + 255) / 256, 256, 0, stream>>>(fW, fWb, 256, 8, 4, 64,
                                                0, 0, 2, tot);

  k_time_inp<<<BN / 4, 256, 0, stream>>>(x, sigma, state, tW1, tb1, tW2, tb2,
                                         inpHi, inpLo, inpMid);
  k_gate<<<BN / TMG, 256, 0, stream>>>(inpHi, inpLo, inpMid, gW1b, gb1, gW2b, gb2,
                                       topk_idx, topk_w, counts, ent);
  k_aux<<<1, 64, 0, stream>>>(counts, ent, offsets, tbk, out + (size_t)BN * AD);
  k_scatter<<<BN / 256, 256, 0, stream>>>(topk_idx, topk_w, offsets, cursor,
                                          slot_row, rslot);
  k_expert<<<GRID_E, 256, 0, stream>>>(inpHi, inpLo, eW1b, eb1, eW2b, eb2,
                                       eW3b, eb3, fWb, offsets, counts, tbk,
                                       slot_row, eout);
  k_final<<<(BN * AD + 255) / 256, 256, 0, stream>>>(x, sigma, fb, rslot,
                                                     topk_w, eout, out);
}

// Round 8
// 503.089 us; speedup vs baseline: 1.0566x; 1.0566x over previous
//
#include <hip/hip_runtime.h>
#include <math.h>

#define BN 32768
#define INDP 352      // padded input width (336 -> 352, zero-filled)
#define HD 256
#define AD 64
#define EN 16
#define TME 32        // expert tile rows
#define TMG 16        // gate tile rows
#define STOT (BN * 4)
#define GRID_E 4112   // 8 * 514 >= max tiles (4111)
#define CHUNK_E 514

typedef __attribute__((ext_vector_type(8))) short s8v;
typedef __attribute__((ext_vector_type(4))) float f4v;
typedef unsigned short u16;

__device__ __forceinline__ u16 f2bf(float x) {
  unsigned u = __float_as_uint(x);
  return (u16)((u + 0x7fffu + ((u >> 16) & 1u)) >> 16);
}
__device__ __forceinline__ float bf2f(u16 h) { return __uint_as_float(((unsigned)h) << 16); }
__device__ __forceinline__ float rcpf(float a) { float r; asm("v_rcp_f32 %0, %1" : "=v"(r) : "v"(a)); return r; }
// mish(x) = x*tanh(softplus(x)) = x*(u^2+2u)/(u^2+2u+2), u=e^x (exact algebraic rewrite)
__device__ __forceinline__ float mishf(float x) {
  float xc = fminf(x, 30.f);
  float u = __expf(xc);
  float w = fmaf(u, u, u + u);
  return x * w * rcpf(w + 2.f);
}
__device__ __forceinline__ f4v mfma16(s8v a, s8v b, f4v c) {
  return __builtin_amdgcn_mfma_f32_16x16x32_bf16(a, b, c, 0, 0, 0);
}
__device__ __forceinline__ void pack8(const u16* q, u16* d) {
  uint4 u;
  u.x = q[0] | ((unsigned)q[1] << 16); u.y = q[2] | ((unsigned)q[3] << 16);
  u.z = q[4] | ((unsigned)q[5] << 16); u.w = q[6] | ((unsigned)q[7] << 16);
  *(uint4*)d = u;
}

// ---- pipelined operand helpers (explicit two-set double buffering) ----
__device__ __forceinline__ void ldB4(const u16* __restrict__ W, int s, int wn, int l,
                                     s8v (&bh)[4], s8v (&bl)[4]) {
  #pragma unroll
  for (int j = 0; j < 4; ++j) {
    const u16* pb = W + (size_t)((s * 16 + wn * 4 + j) * 2) * 512 + l * 8;
    bh[j] = *(const s8v*)pb;
    bl[j] = *(const s8v*)(pb + 512);
  }
}
__device__ __forceinline__ void ldA1(const u16* __restrict__ pHi, const u16* __restrict__ pLo,
                                     const size_t (&rbase)[2], int s, int g,
                                     s8v (&ah)[2], s8v (&al)[2]) {
  #pragma unroll
  for (int mt = 0; mt < 2; ++mt) {
    size_t off = rbase[mt] + s * 32 + g * 8;
    ah[mt] = *(const s8v*)(pHi + off);
    al[mt] = *(const s8v*)(pLo + off);
  }
}
__device__ __forceinline__ void ldA2(const u16* __restrict__ sHi, const u16* __restrict__ sLo,
                                     int s, int g, int r16, int swz,
                                     s8v (&ah)[2], s8v (&al)[2]) {
  int ec = (s * 32 + g * 8) ^ swz;
  #pragma unroll
  for (int mt = 0; mt < 2; ++mt) {
    int row = mt * 16 + r16;
    ah[mt] = *(const s8v*)&sHi[row * 256 + ec];
    al[mt] = *(const s8v*)&sLo[row * 256 + ec];
  }
}
__device__ __forceinline__ void fmas24(f4v (&acc)[2][4], const s8v (&ah)[2], const s8v (&al)[2],
                                       const s8v (&bh)[4], const s8v (&bl)[4]) {
  #pragma unroll
  for (int mt = 0; mt < 2; ++mt)
    #pragma unroll
    for (int j = 0; j < 4; ++j) acc[mt][j] = mfma16(ah[mt], bh[j], acc[mt][j]);
  #pragma unroll
  for (int mt = 0; mt < 2; ++mt)
    #pragma unroll
    for (int j = 0; j < 4; ++j) acc[mt][j] = mfma16(al[mt], bh[j], acc[mt][j]);
  #pragma unroll
  for (int mt = 0; mt < 2; ++mt)
    #pragma unroll
    for (int j = 0; j < 4; ++j) acc[mt][j] = mfma16(ah[mt], bl[j], acc[mt][j]);
}

// ------- weight prep (device body) -------
__device__ __forceinline__ void prep_seg(const float* __restrict__ src, u16* __restrict__ dst,
                                         int Ksrc, int NT, int N,
                                         long sStride, long dStride, int NP, int idx) {
  int l = idx & 63;
  int t = idx >> 6;
  int nt = t % NT; t /= NT;
  int Spad = (Ksrc + 31) / 32;
  int s = t % Spad; t /= Spad;
  int m = t;
  const float* sp = src + (size_t)m * sStride;
  int n = nt * 16 + (l & 15);
  int kb = s * 32 + (l >> 4) * 8;
  u16 q0[8], q1[8], q2[8];
  #pragma unroll
  for (int i = 0; i < 8; ++i) {
    int k = kb + i;
    float v = (k < Ksrc) ? sp[(size_t)k * N + n] : 0.f;
    u16 a = f2bf(v); float r1 = v - bf2f(a);
    u16 b = f2bf(r1); float r2 = r1 - bf2f(b);
    q0[i] = a; q1[i] = b; q2[i] = f2bf(r2);
  }
  u16* d = dst + (size_t)m * dStride + (size_t)((s * NT + nt) * NP) * 512 + l * 8;
  pack8(q0, d);
  pack8(q1, d + 512);
  if (NP == 3) pack8(q2, d + 1024);
}

// single fused prep launch: all 6 weight tensors + scalar init.
// segment sizes (threads): 180224, 131072, 131072, 11264, 512, 2048 — all /256.
__global__ void k_prep_all(const float* __restrict__ eW1, const float* __restrict__ eW2,
                           const float* __restrict__ eW3, const float* __restrict__ gW1,
                           const float* __restrict__ gW2, const float* __restrict__ fW,
                           u16* __restrict__ eW1b, u16* __restrict__ eW2b,
                           u16* __restrict__ eW3b, u16* __restrict__ gW1b,
                           u16* __restrict__ gW2b, u16* __restrict__ fWb,
                           int* __restrict__ counts, int* __restrict__ cursor,
                           float* __restrict__ ent) {
  int idx = blockIdx.x * 256 + threadIdx.x;
  if (idx < 180224) { prep_seg(eW1, eW1b, 336, 16, 256, (long)336 * 256, 180224, 2, idx); return; }
  idx -= 180224;
  if (idx < 131072) { prep_seg(eW2, eW2b, 256, 16, 256, (long)256 * 256, 131072, 2, idx); return; }
  idx -= 131072;
  if (idx < 131072) { prep_seg(eW3, eW3b, 256, 16, 256, (long)256 * 256, 131072, 2, idx); return; }
  idx -= 131072;
  if (idx < 11264) { prep_seg(gW1, gW1b, 336, 16, 256, 0, 0, 3, idx); return; }
  idx -= 11264;
  if (idx < 512) { prep_seg(gW2, gW2b, 256, 1, 16, 0, 0, 3, idx); return; }
  idx -= 512;
  if (idx < 2048) { prep_seg(fW, fWb, 256, 4, 64, 0, 0, 2, idx); return; }
  idx -= 2048;
  if (idx < 16) { counts[idx] = 0; cursor[idx] = 0; }
  if (idx == 16) *ent = 0.f;
}

// ------- time embedding + input assembly (3 split-bf16 planes) + out zeroing -------
__global__ void k_time_inp(const float* __restrict__ x, const float* __restrict__ sigma,
                           const float* __restrict__ state,
                           const float* __restrict__ tW1, const float* __restrict__ tb1,
                           const float* __restrict__ tW2, const float* __restrict__ tb2,
                           u16* __restrict__ p0, u16* __restrict__ p1, u16* __restrict__ p2,
                           float* __restrict__ out) {
  out[blockIdx.x * 256 + threadIdx.x] = 0.f;  // exact 1:1 with BN*AD
  const int wv = threadIdx.x >> 6;
  const int lane = threadIdx.x & 63;
  const int row = blockIdx.x * 4 + wv;
  const float sg = sigma[row];
  const float rt = 250.0f * logf(sg + 1e-44f);
  float pe = 0.f;
  if (lane < 16) {
    int j = lane & 7;
    float f = expf(-1.3157629102823121f * (float)j);  // -ln(10000)/7 * j
    float ang = rt * f;
    pe = (lane < 8) ? sinf(ang) : cosf(ang);
  }
  float h1;
  {
    float acc = 0.f;
    int j = lane & 31;
    #pragma unroll
    for (int i = 0; i < 16; ++i) {
      float p = __shfl(pe, i, 64);
      acc = fmaf(p, tW1[i * 32 + j], acc);
    }
    acc += tb1[j];
    float sp = log1pf(expf(acc));
    h1 = acc * tanhf(sp);
  }
  float t2;
  {
    float acc = 0.f;
    int j = lane & 15;
    #pragma unroll
    for (int i = 0; i < 32; ++i) {
      float h = __shfl(h1, i, 64);
      acc = fmaf(h, tW2[i * 16 + j], acc);
    }
    t2 = acc + tb2[j];
  }
  const float c_in = rsqrtf(sg * sg + 0.25f);
  u16* r0 = p0 + (size_t)row * INDP;
  u16* r1 = p1 + (size_t)row * INDP;
  u16* r2 = p2 + (size_t)row * INDP;
  auto wsplit = [&](int c, float v) {
    u16 a = f2bf(v); float ra = v - bf2f(a);
    u16 b = f2bf(ra); float rb = ra - bf2f(b);
    r0[c] = a; r1[c] = b; r2[c] = f2bf(rb);
  };
  wsplit(lane, c_in * x[row * 64 + lane]);
  if (lane < 16) wsplit(64 + lane, t2);
  #pragma unroll
  for (int r = 0; r < 4; ++r)
    wsplit(80 + r * 64 + lane, state[(size_t)row * 256 + r * 64 + lane]);
  if (lane < 16) { r0[336 + lane] = 0; r1[336 + lane] = 0; r2[336 + lane] = 0; }
}

// ------- gate: TMG=16, all-MFMA (6-term L1, 6-term L2), 3 H-planes in LDS -------
__global__ __launch_bounds__(256, 4) void k_gate(
    const u16* __restrict__ p0, const u16* __restrict__ p1, const u16* __restrict__ p2,
    const u16* __restrict__ gW1b, const float* __restrict__ gb1,
    const u16* __restrict__ gW2b, const float* __restrict__ gb2,
    int* __restrict__ topk_idx, float* __restrict__ topk_w,
    int* __restrict__ counts, float* __restrict__ ent_sum) {
  __shared__ __align__(16) u16 sH0[TMG * 256];
  __shared__ __align__(16) u16 sH1[TMG * 256];
  __shared__ __align__(16) u16 sH2[TMG * 256];
  __shared__ float sLog[TMG * 16];
  __shared__ int scnt[16];
  const int tid = threadIdx.x;
  const int l = tid & 63, wn = tid >> 6;
  const int g = l >> 4, r16 = l & 15;
  const int row0 = blockIdx.x * TMG;
  const int swz = (r16 & 7) << 3;
  if (tid < 16) scnt[tid] = 0;

  f4v acc[4];
  #pragma unroll
  for (int j = 0; j < 4; ++j) acc[j] = (f4v){0.f, 0.f, 0.f, 0.f};

  #pragma unroll
  for (int s = 0; s < 11; ++s) {
    s8v a0, a1, a2, b0[4], b1[4], b2[4];
    {
      size_t off = (size_t)(row0 + r16) * INDP + s * 32 + g * 8;
      a0 = *(const s8v*)(p0 + off);
      a1 = *(const s8v*)(p1 + off);
      a2 = *(const s8v*)(p2 + off);
    }
    #pragma unroll
    for (int j = 0; j < 4; ++j) {
      const u16* pb = gW1b + (size_t)((s * 16 + wn * 4 + j) * 3) * 512 + l * 8;
      b0[j] = *(const s8v*)pb;
      b1[j] = *(const s8v*)(pb + 512);
      b2[j] = *(const s8v*)(pb + 1024);
    }
    #pragma unroll
    for (int j = 0; j < 4; ++j) acc[j] = mfma16(a0, b0[j], acc[j]);
    #pragma unroll
    for (int j = 0; j < 4; ++j) acc[j] = mfma16(a0, b1[j], acc[j]);
    #pragma unroll
    for (int j = 0; j < 4; ++j) acc[j] = mfma16(a1, b0[j], acc[j]);
    #pragma unroll
    for (int j = 0; j < 4; ++j) acc[j] = mfma16(a1, b1[j], acc[j]);
    #pragma unroll
    for (int j = 0; j < 4; ++j) acc[j] = mfma16(a0, b2[j], acc[j]);
    #pragma unroll
    for (int j = 0; j < 4; ++j) acc[j] = mfma16(a2, b0[j], acc[j]);
  }
  // relu + 3-way split into LDS planes (swizzled)
  #pragma unroll
  for (int j = 0; j < 4; ++j) {
    float bj = gb1[wn * 64 + j * 16 + r16];
    #pragma unroll
    for (int r = 0; r < 4; ++r) {
      int row = g * 4 + r;
      int col = wn * 64 + j * 16 + r16;
      float v = fmaxf(acc[j][r] + bj, 0.f);
      u16 h0 = f2bf(v); float ra = v - bf2f(h0);
      u16 h1 = f2bf(ra); float rb = ra - bf2f(h1);
      int ec = col ^ ((row & 7) << 3);
      sH0[row * 256 + ec] = h0;
      sH1[row * 256 + ec] = h1;
      sH2[row * 256 + ec] = f2bf(rb);
    }
  }
  __syncthreads();

  // L2: 256 -> 16, 6-term, all waves compute redundantly
  f4v l2 = (f4v){0.f, 0.f, 0.f, 0.f};
  #pragma unroll
  for (int s = 0; s < 8; ++s) {
    const u16* pb = gW2b + (size_t)(s * 3) * 512 + l * 8;
    s8v b0 = *(const s8v*)pb;
    s8v b1 = *(const s8v*)(pb + 512);
    s8v b2 = *(const s8v*)(pb + 1024);
    int ec = (s * 32 + g * 8) ^ swz;
    s8v a0 = *(const s8v*)&sH0[r16 * 256 + ec];
    s8v a1 = *(const s8v*)&sH1[r16 * 256 + ec];
    s8v a2 = *(const s8v*)&sH2[r16 * 256 + ec];
    l2 = mfma16(a0, b0, l2);
    l2 = mfma16(a0, b1, l2);
    l2 = mfma16(a1, b0, l2);
    l2 = mfma16(a1, b1, l2);
    l2 = mfma16(a0, b2, l2);
    l2 = mfma16(a2, b0, l2);
  }
  if (wn == 0) {
    #pragma unroll
    for (int r = 0; r < 4; ++r)
      sLog[(g * 4 + r) * 16 + r16] = l2[r] + gb2[r16];
  }
  __syncthreads();

  float entc = 0.f;
  if (tid < TMG) {
    const int row = row0 + tid;
    float gx[16], mx = -1e30f;
    #pragma unroll
    for (int e = 0; e < 16; ++e) { gx[e] = sLog[tid * 16 + e]; mx = fmaxf(mx, gx[e]); }
    float p[16], s = 0.f;
    #pragma unroll
    for (int e = 0; e < 16; ++e) { p[e] = expf(gx[e] - mx); s += p[e]; }
    const float inv = 1.f / s;
    #pragma unroll
    for (int e = 0; e < 16; ++e) {
      float pr = p[e] * inv;
      entc -= pr * logf(pr + 1e-9f);
    }
    int idxs[4]; float scs[4];
    unsigned used = 0;
    float wsum = 1e-9f;
    #pragma unroll
    for (int k = 0; k < 4; ++k) {
      int be = 0; float bv = -1.f;
      #pragma unroll
      for (int e = 0; e < 16; ++e) {
        float pr = p[e] * inv;
        if (!((used >> e) & 1u) && pr > bv) { bv = pr; be = e; }
      }
      used |= (1u << be);
      idxs[k] = be; scs[k] = bv;
      wsum += bv;
    }
    #pragma unroll
    for (int k = 0; k < 4; ++k) {
      topk_idx[row * 4 + k] = idxs[k];
      topk_w[row * 4 + k] = scs[k] / wsum;
      atomicAdd(&scnt[idxs[k]], 1);
    }
  }
  if (tid < 64) {
    #pragma unroll
    for (int off = 32; off > 0; off >>= 1) entc += __shfl_down(entc, off, 64);
  }
  if (tid == 0) atomicAdd(ent_sum, entc);
  __syncthreads();
  if (tid < 16 && scnt[tid] > 0) atomicAdd(&counts[tid], scnt[tid]);
}

// ---------------- offsets + aux loss ----------------
__global__ void k_aux(const int* __restrict__ counts, const float* __restrict__ ent_sum,
                      int* __restrict__ offsets, int* __restrict__ tbk,
                      float* __restrict__ aux_out) {
  if (threadIdx.x == 0) {
    int off = 0, t = 0;
    float load[16], mean = 0.f;
    for (int e = 0; e < 16; ++e) {
      offsets[e] = off; tbk[e] = t;
      int c = counts[e];
      off += c;
      t += (c + TME - 1) / TME;
      load[e] = (float)c / (32768.0f + 1e-9f);
      mean += load[e];
    }
    offsets[16] = off; tbk[16] = t;
    mean *= (1.f / 16.f);
    float var = 0.f;
    for (int e = 0; e < 16; ++e) { float d = load[e] - mean; var += d * d; }
    var *= (1.f / 15.f);
    *aux_out = var + ent_sum[0] * (1.0f / 32768.0f);
  }
}

// ------- scatter: block-aggregated (16 global atomics per block) -------
__global__ void k_scatter(const int* __restrict__ topk_idx, const float* __restrict__ topk_w,
                          const int* __restrict__ offsets, int* __restrict__ cursor,
                          int* __restrict__ slot_row, float* __restrict__ slot_w) {
  __shared__ int cnt[16];
  __shared__ int base[16];
  const int tid = threadIdx.x;
  if (tid < 16) cnt[tid] = 0;
  __syncthreads();
  const int row = blockIdx.x * 256 + tid;
  int e4[4]; float w4[4]; int lp[4];
  #pragma unroll
  for (int k = 0; k < 4; ++k) {
    e4[k] = topk_idx[row * 4 + k];
    w4[k] = topk_w[row * 4 + k];
    lp[k] = atomicAdd(&cnt[e4[k]], 1);
  }
  __syncthreads();
  if (tid < 16) base[tid] = atomicAdd(&cursor[tid], cnt[tid]);
  __syncthreads();
  #pragma unroll
  for (int k = 0; k < 4; ++k) {
    int s = offsets[e4[k]] + base[e4[k]] + lp[k];
    slot_row[s] = row;
    slot_w[s] = w4[k];
  }
}

// ------- fused expert: TME=32, 4 waves; explicit register double-buffer pipeline -------
__global__ __launch_bounds__(256, 3) void k_expert(
    const u16* __restrict__ inpHi, const u16* __restrict__ inpLo,
    const u16* __restrict__ eW1b, const float* __restrict__ eb1,
    const u16* __restrict__ eW2b, const float* __restrict__ eb2,
    const u16* __restrict__ eW3b, const float* __restrict__ eb3,
    const u16* __restrict__ fWb,
    const int* __restrict__ offsets, const int* __restrict__ counts,
    const int* __restrict__ tbk, const int* __restrict__ slot_row,
    const float* __restrict__ slot_w, float* __restrict__ out) {
  __shared__ __align__(16) u16 sHi[TME * 256];
  __shared__ __align__(16) u16 sLo[TME * 256];
  __shared__ int sRows[TME];
  __shared__ float sWv[TME];

  // XCD-chunked bijective remap
  const int bid = (blockIdx.x & 7) * CHUNK_E + (blockIdx.x >> 3);
  if (bid >= tbk[16]) return;
  int e = 0;
  #pragma unroll
  for (int i = 1; i < 16; ++i)
    if (bid >= tbk[i]) e = i;
  const int tile = bid - tbk[e];
  const int cnt = counts[e];
  const int s0 = offsets[e] + tile * TME;
  const int nr = min(TME, cnt - tile * TME);
  const int tid = threadIdx.x;
  const int l = tid & 63;
  const int wn = tid >> 6;          // 0..3 (N quarter)
  const int g = l >> 4, r16 = l & 15;
  const int swz = (r16 & 7) << 3;

  if (tid < TME) {
    sRows[tid] = (tid < nr) ? slot_row[s0 + tid] : slot_row[s0];
    sWv[tid] = (tid < nr) ? slot_w[s0 + tid] : 0.f;
  }
  __syncthreads();

  size_t rbase[2];
  rbase[0] = (size_t)sRows[r16] * INDP;
  rbase[1] = (size_t)sRows[16 + r16] * INDP;

  f4v acc[2][4];
  #pragma unroll
  for (int i = 0; i < 2; ++i)
    #pragma unroll
    for (int j = 0; j < 4; ++j) acc[i][j] = (f4v){0.f, 0.f, 0.f, 0.f};

  // ---- layer 1: K=352 (11 steps), A global, B global; 2-deep reg pipeline ----
  const u16* W1 = eW1b + (size_t)e * 180224;
  {
    s8v ahA[2], alA[2], bhA[4], blA[4];
    s8v ahB[2], alB[2], bhB[4], blB[4];
    ldA1(inpHi, inpLo, rbase, 0, g, ahA, alA);
    ldB4(W1, 0, wn, l, bhA, blA);
    #pragma unroll
    for (int s2 = 0; s2 < 5; ++s2) {
      ldA1(inpHi, inpLo, rbase, 2 * s2 + 1, g, ahB, alB);
      ldB4(W1, 2 * s2 + 1, wn, l, bhB, blB);
      fmas24(acc, ahA, alA, bhA, blA);
      ldA1(inpHi, inpLo, rbase, 2 * s2 + 2, g, ahA, alA);
      ldB4(W1, 2 * s2 + 2, wn, l, bhA, blA);
      fmas24(acc, ahB, alB, bhB, blB);
    }
    fmas24(acc, ahA, alA, bhA, blA);   // s = 10
  }
  {
    const float* b1 = eb1 + e * HD;
    #pragma unroll
    for (int mt = 0; mt < 2; ++mt)
      #pragma unroll
      for (int j = 0; j < 4; ++j) {
        float bj = b1[wn * 64 + j * 16 + r16];
        #pragma unroll
        for (int r = 0; r < 4; ++r) {
          int row = mt * 16 + g * 4 + r;
          int col = wn * 64 + j * 16 + r16;
          float v = mishf(acc[mt][j][r] + bj);
          u16 h = f2bf(v);
          int ec = col ^ ((row & 7) << 3);
          sHi[row * 256 + ec] = h;
          sLo[row * 256 + ec] = f2bf(v - bf2f(h));
        }
      }
  }
  __syncthreads();

  // ---- layers 2 & 3: K=256 (8 steps), A LDS, B global; 2-deep reg pipeline ----
  #pragma unroll 1
  for (int L = 0; L < 2; ++L) {
    const u16* Wb = (L == 0 ? eW2b : eW3b) + (size_t)e * 131072;
    const float* bb = (L == 0 ? eb2 : eb3) + e * HD;
    f4v a2[2][4];
    #pragma unroll
    for (int i = 0; i < 2; ++i)
      #pragma unroll
      for (int j = 0; j < 4; ++j) a2[i][j] = (f4v){0.f, 0.f, 0.f, 0.f};
    {
      s8v ahA[2], alA[2], bhA[4], blA[4];
      s8v ahB[2], alB[2], bhB[4], blB[4];
      ldA2(sHi, sLo, 0, g, r16, swz, ahA, alA);
      ldB4(Wb, 0, wn, l, bhA, blA);
      #pragma unroll
      for (int s2 = 0; s2 < 4; ++s2) {
        ldA2(sHi, sLo, 2 * s2 + 1, g, r16, swz, ahB, alB);
        ldB4(Wb, 2 * s2 + 1, wn, l, bhB, blB);
        fmas24(a2, ahA, alA, bhA, blA);
        if (s2 < 3) {
          ldA2(sHi, sLo, 2 * s2 + 2, g, r16, swz, ahA, alA);
          ldB4(Wb, 2 * s2 + 2, wn, l, bhA, blA);
        }
        fmas24(a2, ahB, alB, bhB, blB);
      }
    }
    __syncthreads();  // all reads of previous acts complete
    #pragma unroll
    for (int mt = 0; mt < 2; ++mt)
      #pragma unroll
      for (int j = 0; j < 4; ++j) {
        float bj = bb[wn * 64 + j * 16 + r16];
        #pragma unroll
        for (int r = 0; r < 4; ++r) {
          int row = mt * 16 + g * 4 + r;
          int col = wn * 64 + j * 16 + r16;
          float v = mishf(a2[mt][j][r] + bj);
          u16 h = f2bf(v);
          int ec = col ^ ((row & 7) << 3);
          sHi[row * 256 + ec] = h;
          sLo[row * 256 + ec] = f2bf(v - bf2f(h));
        }
      }
    __syncthreads();
  }

  // ---- final projection: K=256 (8 steps) -> N=64; wave wn owns cols wn*16.. ----
  f4v a3[2];
  a3[0] = (f4v){0.f, 0.f, 0.f, 0.f};
  a3[1] = (f4v){0.f, 0.f, 0.f, 0.f};
  {
    s8v ahA[2], alA[2], ahB[2], alB[2];
    s8v bhA, blA, bhB, blB;
    auto ldBF = [&](int s, s8v& bh, s8v& bl) {
      const u16* pb = fWb + (size_t)((s * 4 + wn) * 2) * 512 + l * 8;
      bh = *(const s8v*)pb;
      bl = *(const s8v*)(pb + 512);
    };
    auto fmas6 = [&](const s8v (&ah)[2], const s8v (&al)[2], s8v bh, s8v bl) {
      a3[0] = mfma16(ah[0], bh, a3[0]);
      a3[1] = mfma16(ah[1], bh, a3[1]);
      a3[0] = mfma16(al[0], bh, a3[0]);
      a3[1] = mfma16(al[1], bh, a3[1]);
      a3[0] = mfma16(ah[0], bl, a3[0]);
      a3[1] = mfma16(ah[1], bl, a3[1]);
    };
    ldA2(sHi, sLo, 0, g, r16, swz, ahA, alA);
    ldBF(0, bhA, blA);
    #pragma unroll
    for (int s2 = 0; s2 < 4; ++s2) {
      ldA2(sHi, sLo, 2 * s2 + 1, g, r16, swz, ahB, alB);
      ldBF(2 * s2 + 1, bhB, blB);
      fmas6(ahA, alA, bhA, blA);
      if (s2 < 3) {
        ldA2(sHi, sLo, 2 * s2 + 2, g, r16, swz, ahA, alA);
        ldBF(2 * s2 + 2, bhA, blA);
      }
      fmas6(ahB, alB, bhB, blB);
    }
  }
  #pragma unroll
  for (int mt = 0; mt < 2; ++mt)
    #pragma unroll
    for (int r = 0; r < 4; ++r) {
      int rl = mt * 16 + g * 4 + r;
      if (rl < nr) {
        float v = a3[mt][r] * sWv[rl];
        atomicAdd(&out[(size_t)sRows[rl] * AD + wn * 16 + r16], v);
      }
    }
}

// ---------------- epilogue ----------------
__global__ void k_final(const float* __restrict__ x, const float* __restrict__ sigma,
                        const float* __restrict__ fb, float* __restrict__ out) {
  int i = blockIdx.x * 256 + threadIdx.x;
  if (i >= BN * AD) return;
  int row = i >> 6, c = i & 63;
  float sg = sigma[row];
  float sm = sg - 0.002f;
  float c_skip = 0.25f / (sm * sm + 0.25f);
  float c_out = sm * 0.5f * rsqrtf(sg * sg + 0.25f);
  float d = c_out * (out[i] + fb[c]) + c_skip * x[i];
  out[i] = fminf(fmaxf(d, -1.f), 1.f);
}

extern "C" void kernel_launch(void* const* d_in, const int* in_sizes, int n_in,
                              void* d_out, int out_size, void* d_ws, size_t ws_size,
                              hipStream_t stream) {
  const float* x     = (const float*)d_in[0];
  const float* sigma = (const float*)d_in[1];
  const float* state = (const float*)d_in[2];
  const float* tW1   = (const float*)d_in[3];
  const float* tb1   = (const float*)d_in[4];
  const float* tW2   = (const float*)d_in[5];
  const float* tb2   = (const float*)d_in[6];
  const float* gW1   = (const float*)d_in[7];
  const float* gb1   = (const float*)d_in[8];
  const float* gW2   = (const float*)d_in[9];
  const float* gb2   = (const float*)d_in[10];
  const float* eW1   = (const float*)d_in[11];
  const float* eb1   = (const float*)d_in[12];
  const float* eW2   = (const float*)d_in[13];
  const float* eb2   = (const float*)d_in[14];
  const float* eW3   = (const float*)d_in[15];
  const float* eb3   = (const float*)d_in[16];
  const float* fW    = (const float*)d_in[17];
  const float* fb    = (const float*)d_in[18];
  float* out = (float*)d_out;

  char* p = (char*)d_ws;
  auto alloc = [&](size_t bytes) { void* r = (void*)p; p += (bytes + 255) & ~(size_t)255; return r; };
  u16* inpHi  = (u16*)alloc((size_t)BN * INDP * 2);
  u16* inpLo  = (u16*)alloc((size_t)BN * INDP * 2);
  u16* inpMid = (u16*)alloc((size_t)BN * INDP * 2);
  u16* gW1b   = (u16*)alloc((size_t)11 * 16 * 3 * 512 * 2);
  u16* gW2b   = (u16*)alloc((size_t)8 * 3 * 512 * 2);
  u16* eW1b   = (u16*)alloc((size_t)16 * 180224 * 2);
  u16* eW2b   = (u16*)alloc((size_t)16 * 131072 * 2);
  u16* eW3b   = (u16*)alloc((size_t)16 * 131072 * 2);
  u16* fWb    = (u16*)alloc((size_t)32768 * 2);
  int*   topk_idx = (int*)alloc((size_t)BN * 4 * 4);
  float* topk_w   = (float*)alloc((size_t)BN * 4 * 4);
  int*   counts   = (int*)alloc(64);
  int*   cursor   = (int*)alloc(64);
  int*   offsets  = (int*)alloc(68);
  int*   tbk      = (int*)alloc(68);
  float* ent      = (float*)alloc(4);
  int*   slot_row = (int*)alloc((size_t)STOT * 4);
  float* slot_w   = (float*)alloc((size_t)STOT * 4);

  // one fused prep launch (6 weight transforms + scalar init); 1783 blocks
  k_prep_all<<<1783, 256, 0, stream>>>(eW1, eW2, eW3, gW1, gW2, fW,
                                       eW1b, eW2b, eW3b, gW1b, gW2b, fWb,
                                       counts, cursor, ent);
  k_time_inp<<<BN / 4, 256, 0, stream>>>(x, sigma, state, tW1, tb1, tW2, tb2,
                                         inpHi, inpLo, inpMid, out);
  k_gate<<<BN / TMG, 256, 0, stream>>>(inpHi, inpLo, inpMid, gW1b, gb1, gW2b, gb2,
                                       topk_idx, topk_w, counts, ent);
  k_aux<<<1, 64, 0, stream>>>(counts, ent, offsets, tbk, out + (size_t)BN * AD);
  k_scatter<<<BN / 256, 256, 0, stream>>>(topk_idx, topk_w, offsets, cursor,
                                          slot_row, slot_w);
  k_expert<<<GRID_E, 256, 0, stream>>>(inpHi, inpLo, eW1b, eb1, eW2b, eb2,
                                       eW3b, eb3, fWb, offsets, counts, tbk,
                                       slot_row, slot_w, out);
  k_final<<<(BN * AD + 255) / 256, 256, 0, stream>>>(x, sigma, fb, out);
}